// Round 10
// baseline (225.926 us; speedup 1.0000x reference)
//
#include <hip/hip_runtime.h>
#include <hip/hip_bf16.h>

// BiAttention, round 12 = r9 body + BARRIER-DOMAIN SPLIT (phase decorrelation):
// r11 post-mortem: QK/PV overlap spilled (FETCH/WRITE grew ~15 MB = scratch);
// within-wave overlap is register-infeasible at 256 regs/wave. r9==r10 showed
// DMA depth isn't the stall either. Remaining theory: all 8 waves/CU sit in
// ONE barrier domain -> phase-locked bursts (MFMA, then VALU, then LDS), no
// cross-phase co-issue; wall 10.3k cyc vs ~3.1k max-pipe. Fix: 512 blocks x
// 4 waves (m-QUARTERS, MT=32, NIT=16), LDS 64KB/block -> TWO independent
// blocks per CU. Same waves/SIMD, same per-CU traffic; only barrier scope
// shrinks and the two blocks' phases decorrelate (m114: independent waves
// co-schedule MFMA+VALU). Quarter partials combine by fp32 atomicAdd into
// seg1/seg2 (prep zeroes them), lsum atomicAdd + mmax atomicMax (uint key)
// into the existing 2-slot ws. All fragment layouts/prep emits unchanged.

typedef __bf16 bf16_t;
typedef bf16_t bf16x4 __attribute__((ext_vector_type(4)));
typedef bf16_t bf16x8 __attribute__((ext_vector_type(8)));
typedef float  f32x16 __attribute__((ext_vector_type(16)));
typedef unsigned int u32x2 __attribute__((ext_vector_type(2)));
typedef unsigned int u32x4 __attribute__((ext_vector_type(4)));

#define NB 8
#define NL 2048
#define NM 2048
#define ND 256
#define OUTW 1024
#define MT 32               // m per block-iteration (one 32-m subtile)
#define NIT 16              // 512 m per block / MT
#define LT 128
#define MEMT_X0 8388608u    // byte offset of transposed bf16 V copy in seg0 space
#define FLASH_LDS 65536     // 2 x (16KB K + 16KB V) double buffer

// seg0 byte-space map: flat byte x -> out byte offset. 1KB chunks of x map to
// 4KB-strided rows of out. Any offset added AFTER omap must not cross a 1KB
// chunk in x-space; chunk steps must be added as multiples of 4096.
__device__ __forceinline__ unsigned omap(unsigned x) {
    return ((x >> 10) << 12) | (x & 1023u);
}

__device__ __forceinline__ void dma16(const void* g, void* l) {
    __builtin_amdgcn_global_load_lds(
        (const __attribute__((address_space(1))) unsigned int*)g,
        (__attribute__((address_space(3))) unsigned int*)l, 16, 0, 0);
}

// ---- Kernel A: mbias + bf16 copies (K fragment-major & V transposed) -------
// grid: 8 b * 64 chunks-of-32m = 512 blocks; 256 thr = 4 waves.
// Also zeroes: seg1+seg2 of its 32 out rows (atomic targets), a 128-float
// stripe of ws_l/ws_m, and (block 0) ws_num/ws_den.
__global__ __launch_bounds__(256) void prep_kernel(
    const float* __restrict__ memory, const float* __restrict__ mask,
    const float* __restrict__ w_memory,
    float* __restrict__ ws_mbias, float* __restrict__ ws_lm,
    float* __restrict__ ws_numden, char* __restrict__ outc)
{
    // rows m (32), cols d (256), row stride 264 (+8 pad: frag-emit read 4-way)
    __shared__ __align__(16) bf16_t lds[32 * 264];

    int b  = blockIdx.x >> 6;
    int mc = blockIdx.x & 63;            // 32-m chunk
    int t  = threadIdx.x, w = t >> 6, lane = t & 63;

    if (blockIdx.x == 0) {               // zero ws_num (2048) + ws_den (8)
        for (int k = t; k < 2056; k += 256) ws_numden[k] = 0.f;
    }
    // zero ws_l + ws_m (64K floats total across 512 blocks)
    if (t < 128) ws_lm[blockIdx.x * 128 + t] = 0.f;
    // zero seg1+seg2 of out rows [blockIdx*32, +32): floats [256,768) per row
    {
        float* outf = (float*)outc;
        float4 z = {0.f, 0.f, 0.f, 0.f};
        int row0 = blockIdx.x * 32;
        #pragma unroll
        for (int k = 0; k < 16; ++k) {
            int idx = k * 256 + t;               // 0..4095
            int r = idx >> 7, e = idx & 127;     // 128 float4 = 512 floats
            *(float4*)(outf + (size_t)(row0 + r) * OUTW + 256 + e * 4) = z;
        }
    }

    float4 wv = *(const float4*)(w_memory + lane * 4);

    #pragma unroll
    for (int it = 0; it < 8; ++it) {
        int rloc = it * 4 + w;                       // 0..31
        int row  = b * NM + mc * 32 + rloc;          // global memory row
        float4 v = *(const float4*)(memory + (size_t)row * ND + lane * 4);
        float s = v.x * wv.x + v.y * wv.y + v.z * wv.z + v.w * wv.w;
        #pragma unroll
        for (int off = 1; off < 64; off <<= 1) s += __shfl_xor(s, off, 64);
        if (lane == 0) ws_mbias[row] = s - 1e30f * (1.0f - mask[row]);
        bf16x4 bv;
        bv[0] = (bf16_t)v.x; bv[1] = (bf16_t)v.y;
        bv[2] = (bf16_t)v.z; bv[3] = (bf16_t)v.w;
        // stage into LDS (K-frag emit + V-transpose emit both read from here)
        *(bf16x4*)(&lds[rloc * 264 + lane * 4]) = bv;
    }
    __syncthreads();

    // K fragment-major emit: 16KB chunk per (b,mc). Byte o of chunk decomposes
    // as ks=o>>10, h=(o>>9)&1, c=(o>>4)&31, e=o&15: holds K[m=mc*32+c]
    // [d=16ks+8h+e/2]. Thread t writes 4 coalesced 16B granules (r=0..3).
    {
        unsigned xbase = ((unsigned)(b * 64 + mc)) * 16384u;
        int c = t & 31, h5 = (t >> 5) & 1, ksh = t >> 6;
        #pragma unroll
        for (int r = 0; r < 4; ++r) {
            bf16x8 g = *(const bf16x8*)(&lds[c * 264 + (4 * r + ksh) * 16 + h5 * 8]);
            *(bf16x8*)(outc + omap(xbase + r * 4096u + (unsigned)t * 16u)) = g;
        }
    }

    // transposed V emit: layout [b][m>>3][d][m&7]; thread t = d column.
    int d = t;
    #pragma unroll
    for (int mc4 = 0; mc4 < 4; ++mc4) {
        bf16x8 pk;
        #pragma unroll
        for (int j = 0; j < 8; ++j) pk[j] = lds[(mc4 * 8 + j) * 264 + d];
        unsigned x = MEMT_X0 +
            2u * ((((unsigned)(b * 256 + mc * 4 + mc4)) * ND + d) * 8);
        *(bf16x8*)(outc + omap(x)) = pk;   // 16B granule, in-chunk ✓
    }
}

// ---- Kernel B: flash attention partials (+ fused idot) ---------------------
// grid 512 = lt*32 + b*4 + q; 4 waves; wave gw owns L rows [gw*32, gw*32+32);
// block owns m-quarter q (512 m, 16 iters x 32 m). Two blocks co-reside per
// CU (64KB LDS) with independent barriers -> phase decorrelation.
// Quarters {0,1} -> seg1/slot0, {2,3} -> seg2/slot1, combined atomically.
__global__ __launch_bounds__(256, 2) void flash_kernel(
    const float* __restrict__ input, const float* __restrict__ dot_scale,
    const float* __restrict__ w_input, const float* __restrict__ ws_mbias,
    const char* __restrict__ outc, float* __restrict__ out,
    float* __restrict__ ws_l, float* __restrict__ ws_m,
    float* __restrict__ ws_idot)
{
    extern __shared__ __align__(16) char smem[];
    // buf0 [0,32768): K(16KB) | V(16KB);  buf1 [32768,65536): same
    // epilogue: patch overlays buf0 (per-wave 4352B; buf0 dead after it=14)

    int bid = blockIdx.x;
    int lt = bid >> 5, b = (bid >> 2) & 7, q = bid & 3;
    // same-(b,q) blocks are bid-stride 32 (≡0 mod 8): shared K/V stays on one XCD
    int l0 = lt * LT;
    int slot = q >> 1;                    // 0: m 0..1023, 1: m 1024..2047
    int t = threadIdx.x, w = t >> 6, lane = t & 63;
    int gw = w;                           // 4 waves, all on L split
    int c = lane & 31, h = lane >> 5;

    // Q fragments in registers (B-operand; col = lane&31 = l, k contiguous d)
    // Fused idot: only q==0 blocks compute it (one per (lt,b)).
    const float* qrow = input + (size_t)(b * NL + l0 + gw * 32 + c) * ND;
    bool do_idot = (q == 0);
    float idot_s = 0.f;
    bf16x8 qf[16];
    #pragma unroll
    for (int ks = 0; ks < 16; ++ks) {
        int d0 = ks * 16 + h * 8;
        float4 a0 = *(const float4*)(qrow + d0);
        float4 a1 = *(const float4*)(qrow + d0 + 4);
        float4 s0 = *(const float4*)(dot_scale + d0);
        float4 s1 = *(const float4*)(dot_scale + d0 + 4);
        if (do_idot) {
            float4 w0 = *(const float4*)(w_input + d0);
            float4 w1 = *(const float4*)(w_input + d0 + 4);
            idot_s += a0.x * w0.x + a0.y * w0.y + a0.z * w0.z + a0.w * w0.w
                    + a1.x * w1.x + a1.y * w1.y + a1.z * w1.z + a1.w * w1.w;
        }
        qf[ks][0] = (bf16_t)(a0.x * s0.x); qf[ks][1] = (bf16_t)(a0.y * s0.y);
        qf[ks][2] = (bf16_t)(a0.z * s0.z); qf[ks][3] = (bf16_t)(a0.w * s0.w);
        qf[ks][4] = (bf16_t)(a1.x * s1.x); qf[ks][5] = (bf16_t)(a1.y * s1.y);
        qf[ks][6] = (bf16_t)(a1.z * s1.z); qf[ks][7] = (bf16_t)(a1.w * s1.w);
    }
    if (do_idot) {
        idot_s += __shfl_xor(idot_s, 32, 64);
        if (lane < 32) ws_idot[b * NL + l0 + gw * 32 + lane] = idot_s;
    }

    // Per-lane DMA source bases (mapped through omap once; later increments
    // stay within-chunk or step whole chunks by multiples of 4096).
    // K fragment-major chunk index: b*64 + q*16 + it; granule i at +i*4096
    // out-bytes; per-iter advance 16384 x-bytes -> +65536 out-bytes.
    unsigned xk = ((unsigned)(b * 64 + q * 16)) * 16384u + (unsigned)lane * 16u;
    const char* kg = outc + omap(xk);
    unsigned xv = MEMT_X0 +
        2u * ((((unsigned)(b * 256 + q * 64 + h)) * ND + c) * 8);
    const char* vg = outc + omap(xv);

    char* buf0 = smem;
    char* buf1 = smem + 32768;

    // 4 waves cooperatively stage the 16KB K + 16KB V tile (8 dma16/wave).
    #define STAGE(nbuf) do {                                                  \
        _Pragma("unroll")                                                     \
        for (int j = 0; j < 4; ++j) {                                         \
            int i = gw * 4 + j;                                               \
            int ks = i >> 3, dt = i & 7;                                      \
            dma16(kg + i * 4096, (nbuf) + i * 1024);                          \
            dma16(vg + ks * 32768 + (dt >> 1) * 4096 + (dt & 1) * 512,        \
                  (nbuf) + 16384 + i * 1024);                                 \
        }                                                                     \
        kg += 65536; vg += 65536; } while (0)

    // prologue: stage tile 0 into buf0
    STAGE(buf0);

    f32x16 oaccT[8];
    #pragma unroll
    for (int i = 0; i < 8; ++i)
        #pragma unroll
        for (int r = 0; r < 16; ++r) oaccT[i][r] = 0.f;
    float lsum = 0.f, mmax = -3e38f;

    const float* mb_base = ws_mbias + b * NM;

    #pragma unroll 1
    for (int it = 0; it < NIT; ++it) {
        int m0 = q * 512 + it * MT;
        asm volatile("s_waitcnt vmcnt(0)" ::: "memory"); // my DMA for cur done
        __syncthreads();                                  // block-local (4 waves)
        const char* cb = (it & 1) ? buf1 : buf0;
        char* nb = (it & 1) ? buf0 : buf1;
        const bf16_t* kb = (const bf16_t*)cb;
        const bf16_t* vb = (const bf16_t*)(cb + 16384);
        if (it + 1 < NIT) { STAGE(nb); }
        // mbias broadcast loads (L1-hot). Own reg r needs
        // m = (r&3) + 8*(r>>2) + 4h -> rows m0+4h+{0,8,16,24}.
        const float* mrow = mb_base + m0 + 4 * h;
        float4 mbv0 = *(const float4*)(mrow);
        float4 mbv1 = *(const float4*)(mrow + 8);
        float4 mbv2 = *(const float4*)(mrow + 16);
        float4 mbv3 = *(const float4*)(mrow + 24);
        // QK: S^T = K . Q^T
        f32x16 S;
        #pragma unroll
        for (int r = 0; r < 16; ++r) S[r] = 0.f;
        #pragma unroll
        for (int ks = 0; ks < 16; ++ks) {
            bf16x8 k0 = *(const bf16x8*)(kb + ks * 512 + lane * 8);
            S = __builtin_amdgcn_mfma_f32_32x32x16_bf16(k0, qf[ks], S, 0, 0, 0);
        }
        // P^T = exp(S^T + mdot), packed to bf16 pairs entirely in registers.
        u32x2 own[4];      // own[g] = bf16 pair-pack of regs r=4g..4g+3
        #pragma unroll
        for (int g = 0; g < 4; ++g) {
            float4 mbv = (g == 0) ? mbv0 : (g == 1) ? mbv1 : (g == 2) ? mbv2 : mbv3;
            bf16x4 tq;
            #pragma unroll
            for (int qq = 0; qq < 4; ++qq) {
                float v = S[g * 4 + qq] +
                          ((qq == 0) ? mbv.x : (qq == 1) ? mbv.y : (qq == 2) ? mbv.z : mbv.w);
                mmax = fmaxf(mmax, v);
                float e = __expf(v);
                lsum += e;
                tq[qq] = (bf16_t)e;
            }
            own[g] = __builtin_bit_cast(u32x2, tq);
        }
        // PV: O^T += V^T . P^T. B-frag (elem e) of lane (c,h) needs
        // m = 16ks + 8h + e: elems 0-3 from half 0, 4-7 from half 1, both at
        // regs r = 4*(2ks+h)+q of lane (c, e>>2) -> lane i<->i+32 exchange.
        #pragma unroll
        for (int ks = 0; ks < 2; ++ks) {
            unsigned oAlo = own[2 * ks].x,     oAhi = own[2 * ks].y;      // g=2ks
            unsigned oBlo = own[2 * ks + 1].x, oBhi = own[2 * ks + 1].y;  // g=2ks+1
            unsigned slo = h ? oAlo : oBlo;    // send group 2ks+(1-h)
            unsigned shi = h ? oAhi : oBhi;
            unsigned rlo = (unsigned)__shfl_xor((int)slo, 32, 64);
            unsigned rhi = (unsigned)__shfl_xor((int)shi, 32, 64);
            unsigned mlo = h ? oBlo : oAlo;    // my group 2ks+h
            unsigned mhi = h ? oBhi : oAhi;
            u32x4 uu;
            uu.x = h ? rlo : mlo;              // elems 0-3 (from half 0)
            uu.y = h ? rhi : mhi;
            uu.z = h ? mlo : rlo;              // elems 4-7 (from half 1)
            uu.w = h ? mhi : rhi;
            bf16x8 pb = __builtin_bit_cast(bf16x8, uu);
            #pragma unroll
            for (int dt = 0; dt < 8; ++dt) {
                bf16x8 vv = *(const bf16x8*)(vb + (ks * 8 + dt) * 512 + lane * 8);
                oaccT[dt] = __builtin_amdgcn_mfma_f32_32x32x16_bf16(vv, pb, oaccT[dt], 0, 0, 0);
            }
        }
    }
    #undef STAGE

    __syncthreads();   // aligned final barrier; buf0 dead (it=15 read buf1)

    // l-sum / row-max: h-halves merge in-wave, then atomic combine of quarters
    mmax = fmaxf(mmax, __shfl_xor(mmax, 32, 64));
    lsum += __shfl_xor(lsum, 32, 64);
    if (lane < 32) {
        int row = b * NL + l0 + gw * 32 + lane;
        atomicAdd(&ws_l[slot * (NB * NL) + row], lsum);
        unsigned u = __float_as_uint(mmax);
        unsigned key = (u >> 31) ? ~u : (u | 0x80000000u);   // monotone f32 key
        atomicMax((unsigned*)ws_m + slot * (NB * NL) + row, key);
    }
    // epilogue: O^T -> coalesced O via per-wave LDS patch, atomicAdd combine.
    // FULLY UNROLLED: oaccT indexed by compile-time constants only.
    {
        float* patch = (float*)(smem + gw * 4352);   // [32 d][stride 33] floats
        float* oseg = out + (size_t)(b * NL + l0 + gw * 32) * OUTW + ND * (1 + slot);
        #pragma unroll
        for (int dt = 0; dt < 8; ++dt) {
            asm volatile("s_waitcnt lgkmcnt(0)" ::: "memory");
            #pragma unroll
            for (int r = 0; r < 16; ++r)
                patch[((r & 3) + 8 * (r >> 2) + 4 * h) * 33 + c] = oaccT[dt][r];
            asm volatile("s_waitcnt lgkmcnt(0)" ::: "memory");
            #pragma unroll
            for (int rr = 0; rr < 16; ++rr) {
                float val = patch[c * 33 + rr * 2 + h];
                atomicAdd(&oseg[(size_t)(rr * 2 + h) * OUTW + dt * 32 + c], val);
            }
        }
    }
}

// ---- Kernel C: output_two numerator/denominator (no separate softmax) ------
// grid 256 = b*32 + slice; LDS pre-reduce cuts ws_num atomics 4x.
// ws_m now holds monotone uint keys -> decode after max.
__global__ __launch_bounds__(256) void o2_kernel(
    const float* __restrict__ input, const float* __restrict__ ws_idot,
    const float* __restrict__ ws_m, float* __restrict__ ws_num,
    float* __restrict__ ws_den)
{
    __shared__ float4 red[256];
    const unsigned* wm = (const unsigned*)ws_m;
    int b = blockIdx.x >> 5, slice = blockIdx.x & 31;
    int t = threadIdx.x;
    int lgrp = t >> 6, d4 = (t & 63) * 4;
    float4 acc = {0.f, 0.f, 0.f, 0.f};
    float esum = 0.f;
    for (int i = 0; i < 16; ++i) {
        int row = b * NL + slice * 64 + lgrp * 16 + i;
        unsigned k0 = wm[row], k1 = wm[NB * NL + row];
        unsigned kk = k0 > k1 ? k0 : k1;
        float m = __uint_as_float((kk >> 31) ? (kk & 0x7FFFFFFFu) : ~kk);
        float e = __expf(ws_idot[row] + m);
        float4 v = *(const float4*)(input + (size_t)row * ND + d4);
        acc.x += e * v.x; acc.y += e * v.y;
        acc.z += e * v.z; acc.w += e * v.w;
        esum += e;
    }
    red[t] = acc;
    __syncthreads();
    if (t < 64) {
        float4 a0 = red[t], a1 = red[t + 64], a2 = red[t + 128], a3 = red[t + 192];
        float* dst = ws_num + b * ND + t * 4;
        atomicAdd(dst + 0, a0.x + a1.x + a2.x + a3.x);
        atomicAdd(dst + 1, a0.y + a1.y + a2.y + a3.y);
        atomicAdd(dst + 2, a0.z + a1.z + a2.z + a3.z);
        atomicAdd(dst + 3, a0.w + a1.w + a2.w + a3.w);
    }
    if ((t & 63) == 0) atomicAdd(ws_den + b, esum);
}

// ---- Kernel D: combine halves + assemble all 4 output segments -------------
__global__ __launch_bounds__(256) void assembly_kernel(
    const float* __restrict__ input, const float* __restrict__ ws_num,
    const float* __restrict__ ws_den, const float* __restrict__ ws_l,
    float* __restrict__ out)
{
    size_t tid = (size_t)blockIdx.x * 256 + threadIdx.x;
    size_t row = tid >> 6;
    int d = (int)(tid & 63) * 4;
    int b = (int)(row >> 11);
    float inv  = 1.0f / (ws_l[row] + ws_l[NB * NL + row]);
    float dinv = 1.0f / ws_den[b];
    float* po = out + row * OUTW;
    float4 in = *(const float4*)(input + row * ND + d);
    float4 pa = *(const float4*)(po + ND + d);
    float4 pb = *(const float4*)(po + 2 * ND + d);
    float4 nu = *(const float4*)(ws_num + b * ND + d);
    float4 o1;
    o1.x = (pa.x + pb.x) * inv; o1.y = (pa.y + pb.y) * inv;
    o1.z = (pa.z + pb.z) * inv; o1.w = (pa.w + pb.w) * inv;
    float4 o2v;
    o2v.x = nu.x * dinv; o2v.y = nu.y * dinv;
    o2v.z = nu.z * dinv; o2v.w = nu.w * dinv;
    *(float4*)(po + d) = in;
    *(float4*)(po + ND + d) = o1;
    float4 qv;
    qv.x = in.x * o1.x; qv.y = in.y * o1.y; qv.z = in.z * o1.z; qv.w = in.w * o1.w;
    *(float4*)(po + 2 * ND + d) = qv;
    float4 r;
    r.x = o2v.x * o1.x; r.y = o2v.y * o1.y; r.z = o2v.z * o1.z; r.w = o2v.w * o1.w;
    *(float4*)(po + 3 * ND + d) = r;
}

// ---- launcher ---------------------------------------------------------------
extern "C" void kernel_launch(void* const* d_in, const int* in_sizes, int n_in,
                              void* d_out, int out_size, void* d_ws, size_t ws_size,
                              hipStream_t stream) {
    const float* input     = (const float*)d_in[0];
    const float* memory    = (const float*)d_in[1];
    const float* mask      = (const float*)d_in[2];
    const float* w_input   = (const float*)d_in[3];
    const float* w_memory  = (const float*)d_in[4];
    const float* dot_scale = (const float*)d_in[5];
    float* out = (float*)d_out;
    char* outc = (char*)d_out;
    float* ws  = (float*)d_ws;

    // ws floats: idot 16K | mbias 16K | l 2x16K | m 2x16K | num 2K | den 8
    float* ws_idot  = ws;
    float* ws_mbias = ws + 16384;
    float* ws_l     = ws + 32768;
    float* ws_m     = ws + 65536;
    float* ws_num   = ws + 98304;
    float* ws_den   = ws + 100352;

    prep_kernel<<<512, 256, 0, stream>>>(memory, mask, w_memory, ws_mbias,
                                         ws_l /* zero l+m (64K contig) */,
                                         ws_num, outc);
    flash_kernel<<<512, 256, FLASH_LDS, stream>>>(input, dot_scale, w_input,
                                                  ws_mbias, outc, out,
                                                  ws_l, ws_m, ws_idot);
    o2_kernel<<<256, 256, 0, stream>>>(input, ws_idot, ws_m, ws_num, ws_den);
    assembly_kernel<<<4096, 256, 0, stream>>>(input, ws_num, ws_den, ws_l, out);
}

// Round 11
// 206.125 us; speedup vs baseline: 1.0961x; 1.0961x over previous
//
#include <hip/hip_runtime.h>
#include <hip/hip_bf16.h>

// BiAttention, round 13 = r9 (best known: flash 68.4us, total 190.9) + ONE
// change: DUAL-S QK CHAINS restored (r6 had them; removed in r7 untested).
// Rationale: m119 says MFMA peak needs 2-8 independent chains; r9's single
// 16-deep dependent chain leaves the matrix pipe ~50% idle during QK
// (2 chains/SIMD). Dual Sa/Sb -> 4 chains/SIMD -> QK ~2080 -> ~1100 cyc/iter.
// Register fit: mbias loads moved AFTER QK so during-QK live = qf(64) +
// Sa(16) + Sb(16) + addr ~ 110 VGPR < 128; AGPR 128 unchanged; 256 total =
// 2 waves/SIMD preserved. Gate: FETCH/WRITE must stay ~31.9/48 MB (growth
// = spill, the r11 failure mode).
// r12's barrier-split + atomic combine REVERTED (cost +28MB WRITE RMW traffic,
// flash 70->102). r10 lesson kept: no counted-vmcnt games around barriers.

typedef __bf16 bf16_t;
typedef bf16_t bf16x4 __attribute__((ext_vector_type(4)));
typedef bf16_t bf16x8 __attribute__((ext_vector_type(8)));
typedef float  f32x16 __attribute__((ext_vector_type(16)));
typedef unsigned int u32x2 __attribute__((ext_vector_type(2)));
typedef unsigned int u32x4 __attribute__((ext_vector_type(4)));

#define NB 8
#define NL 2048
#define NM 2048
#define ND 256
#define OUTW 1024
#define MT 64               // m per block-iteration (2 x 32 subtiles)
#define MH 1024
#define NIT 16              // MH/MT
#define LT 128
#define MEMT_X0 8388608u    // byte offset of transposed bf16 V copy in seg0 space
#define FLASH_LDS 133120    // 2x64KB kv dbuf + 2KB epilogue aux

// seg0 byte-space map: flat byte x -> out byte offset. 1KB chunks of x map to
// 4KB-strided rows of out. Any offset added AFTER omap must not cross a 1KB
// chunk in x-space; chunk steps must be added as multiples of 4096.
__device__ __forceinline__ unsigned omap(unsigned x) {
    return ((x >> 10) << 12) | (x & 1023u);
}

__device__ __forceinline__ void dma16(const void* g, void* l) {
    __builtin_amdgcn_global_load_lds(
        (const __attribute__((address_space(1))) unsigned int*)g,
        (__attribute__((address_space(3))) unsigned int*)l, 16, 0, 0);
}

// ---- Kernel A: mbias + bf16 copies (K fragment-major & V transposed) -------
// grid: 8 b * 64 chunks-of-32m = 512 blocks; 256 thr = 4 waves.
// Block 0 additionally zeroes ws_num/ws_den (consumed by o2 after flash).
__global__ __launch_bounds__(256) void prep_kernel(
    const float* __restrict__ memory, const float* __restrict__ mask,
    const float* __restrict__ w_memory,
    float* __restrict__ ws_mbias, float* __restrict__ ws_numden,
    char* __restrict__ outc)
{
    // rows m (32), cols d (256), row stride 264 (+8 pad: frag-emit read 4-way)
    __shared__ __align__(16) bf16_t lds[32 * 264];

    int b  = blockIdx.x >> 6;
    int mc = blockIdx.x & 63;            // 32-m chunk
    int t  = threadIdx.x, w = t >> 6, lane = t & 63;

    if (blockIdx.x == 0) {               // zero ws_num (2048) + ws_den (8)
        for (int k = t; k < 2056; k += 256) ws_numden[k] = 0.f;
    }

    float4 wv = *(const float4*)(w_memory + lane * 4);

    #pragma unroll
    for (int it = 0; it < 8; ++it) {
        int rloc = it * 4 + w;                       // 0..31
        int row  = b * NM + mc * 32 + rloc;          // global memory row
        float4 v = *(const float4*)(memory + (size_t)row * ND + lane * 4);
        float s = v.x * wv.x + v.y * wv.y + v.z * wv.z + v.w * wv.w;
        #pragma unroll
        for (int off = 1; off < 64; off <<= 1) s += __shfl_xor(s, off, 64);
        if (lane == 0) ws_mbias[row] = s - 1e30f * (1.0f - mask[row]);
        bf16x4 bv;
        bv[0] = (bf16_t)v.x; bv[1] = (bf16_t)v.y;
        bv[2] = (bf16_t)v.z; bv[3] = (bf16_t)v.w;
        // stage into LDS (K-frag emit + V-transpose emit both read from here)
        *(bf16x4*)(&lds[rloc * 264 + lane * 4]) = bv;
    }
    __syncthreads();

    // K fragment-major emit: 16KB chunk per (b,mc). Byte o of chunk decomposes
    // as ks=o>>10, h=(o>>9)&1, c=(o>>4)&31, e=o&15: holds K[m=mc*32+c]
    // [d=16ks+8h+e/2]. Thread t writes 4 coalesced 16B granules (r=0..3):
    // o = r*4096 + t*16 -> ks=4r+(t>>6), h=(t>>5)&1, c=t&31.
    {
        unsigned xbase = ((unsigned)(b * 64 + mc)) * 16384u;
        int c = t & 31, h5 = (t >> 5) & 1, ksh = t >> 6;
        #pragma unroll
        for (int r = 0; r < 4; ++r) {
            bf16x8 g = *(const bf16x8*)(&lds[c * 264 + (4 * r + ksh) * 16 + h5 * 8]);
            *(bf16x8*)(outc + omap(xbase + r * 4096u + (unsigned)t * 16u)) = g;
        }
    }

    // transposed V emit: layout [b][m>>3][d][m&7]; thread t = d column.
    int d = t;
    #pragma unroll
    for (int mc4 = 0; mc4 < 4; ++mc4) {
        bf16x8 pk;
        #pragma unroll
        for (int j = 0; j < 8; ++j) pk[j] = lds[(mc4 * 8 + j) * 264 + d];
        unsigned x = MEMT_X0 +
            2u * ((((unsigned)(b * 256 + mc * 4 + mc4)) * ND + d) * 8);
        *(bf16x8*)(outc + omap(x)) = pk;   // 16B granule, in-chunk ✓
    }
}

// ---- Kernel B: flash attention partials (+ fused idot) ---------------------
// grid 256 = lt*16 + b*2 + half; 8 waves; wave w: gw=w&3 owns L rows
// [gw*32, gw*32+32), grp=w>>2 owns m-subtile grp of each 64-m tile.
__global__ __launch_bounds__(512, 2) void flash_kernel(
    const float* __restrict__ input, const float* __restrict__ dot_scale,
    const float* __restrict__ w_input, const float* __restrict__ ws_mbias,
    const char* __restrict__ outc, float* __restrict__ out,
    float* __restrict__ ws_l, float* __restrict__ ws_m,
    float* __restrict__ ws_idot)
{
    extern __shared__ __align__(16) char smem[];
    // buf0 [0,65536): K_A|K_B|V_A|V_B (16KB each)
    // buf1 [65536,131072): same layout
    // aux  [131072,133120): 4 gw x 512B epilogue lsum/mmax exchange

    int bid = blockIdx.x;
    int half = bid & 1, b = (bid >> 1) & 7, lt = bid >> 4;
    int l0 = lt * LT;
    int m_base = half * MH;
    int t = threadIdx.x, w = t >> 6, lane = t & 63;
    int gw = w & 3, grp = w >> 2;
    int c = lane & 31, h = lane >> 5;

    // Q fragments in registers (B-operand; col = lane&31 = l, k contiguous d)
    // Fused idot: sum unscaled Q row against w_input while it's in registers.
    const float* qrow = input + (size_t)(b * NL + l0 + gw * 32 + c) * ND;
    bool do_idot = (half == 0) && (grp == 0);
    float idot_s = 0.f;
    bf16x8 qf[16];
    #pragma unroll
    for (int ks = 0; ks < 16; ++ks) {
        int d0 = ks * 16 + h * 8;
        float4 a0 = *(const float4*)(qrow + d0);
        float4 a1 = *(const float4*)(qrow + d0 + 4);
        float4 s0 = *(const float4*)(dot_scale + d0);
        float4 s1 = *(const float4*)(dot_scale + d0 + 4);
        if (do_idot) {
            float4 w0 = *(const float4*)(w_input + d0);
            float4 w1 = *(const float4*)(w_input + d0 + 4);
            idot_s += a0.x * w0.x + a0.y * w0.y + a0.z * w0.z + a0.w * w0.w
                    + a1.x * w1.x + a1.y * w1.y + a1.z * w1.z + a1.w * w1.w;
        }
        qf[ks][0] = (bf16_t)(a0.x * s0.x); qf[ks][1] = (bf16_t)(a0.y * s0.y);
        qf[ks][2] = (bf16_t)(a0.z * s0.z); qf[ks][3] = (bf16_t)(a0.w * s0.w);
        qf[ks][4] = (bf16_t)(a1.x * s1.x); qf[ks][5] = (bf16_t)(a1.y * s1.y);
        qf[ks][6] = (bf16_t)(a1.z * s1.z); qf[ks][7] = (bf16_t)(a1.w * s1.w);
    }
    if (do_idot) {
        idot_s += __shfl_xor(idot_s, 32, 64);
        if (lane < 32) ws_idot[b * NL + l0 + gw * 32 + lane] = idot_s;
    }

    // Per-lane DMA source bases (mapped through omap once; later increments
    // stay within-chunk or step whole chunks by multiples of 4096).
    // K fragment-major: chunk (b*64 + half*32 + it*2 + grp), granule i*1024 +
    // lane*16 -> contiguous 1KB per dma16 instruction.
    unsigned xk = ((unsigned)(b * 64 + half * 32 + grp)) * 16384u + (unsigned)lane * 16u;
    const char* kg = outc + omap(xk);
    unsigned xv = MEMT_X0 +
        2u * ((((unsigned)(b * 256 + (m_base >> 3) + grp * 4 + h)) * ND + c) * 8);
    const char* vg = outc + omap(xv);

    char* buf0 = smem;
    char* buf1 = smem + 65536;

    // Each grp's 4 waves cooperatively stage that grp's 16KB K + 16KB V
    // subtile; per-iteration advance 64 m = 32KB x-step -> out step 131072.
    #define STAGE(nbuf) do {                                                  \
        _Pragma("unroll")                                                     \
        for (int j = 0; j < 4; ++j) {                                         \
            int i = gw * 4 + j;                                               \
            int ks = i >> 3, dt = i & 7;                                      \
            dma16(kg + i * 4096, (nbuf) + grp * 16384 + i * 1024);            \
            dma16(vg + ks * 32768 + (dt >> 1) * 4096 + (dt & 1) * 512,        \
                  (nbuf) + 32768 + grp * 16384 + i * 1024);                   \
        }                                                                     \
        kg += 131072; vg += 131072; } while (0)

    // prologue: stage tile 0 into buf0
    STAGE(buf0);

    f32x16 oaccT[8];
    #pragma unroll
    for (int i = 0; i < 8; ++i)
        #pragma unroll
        for (int r = 0; r < 16; ++r) oaccT[i][r] = 0.f;
    float lsum = 0.f, mmax = -3e38f;

    const float* mb_base = ws_mbias + b * NM;

    #pragma unroll 1
    for (int it = 0; it < NIT; ++it) {
        int m0 = m_base + it * MT + grp * 32;
        asm volatile("s_waitcnt vmcnt(0)" ::: "memory"); // my DMA for cur done
        __syncthreads();                                  // all waves' DMA visible
        const char* cb = (it & 1) ? buf1 : buf0;
        char* nb = (it & 1) ? buf0 : buf1;
        const bf16_t* kb = (const bf16_t*)(cb + grp * 16384);
        const bf16_t* vb = (const bf16_t*)(cb + 32768 + grp * 16384);
        if (it + 1 < NIT) {   // stage next tile (safe: barrier above)
            STAGE(nb);
        }
        // QK: S^T = K . Q^T — DUAL independent accumulator chains (Sa even ks,
        // Sb odd ks): 4 chains/SIMD keeps the MFMA pipe issue-bound instead of
        // dependent-latency-bound (m119: peak needs 2-8 chains).
        f32x16 Sa, Sb;
        #pragma unroll
        for (int r = 0; r < 16; ++r) { Sa[r] = 0.f; Sb[r] = 0.f; }
        #pragma unroll
        for (int ks = 0; ks < 16; ks += 2) {
            bf16x8 k0 = *(const bf16x8*)(kb + ks * 512 + lane * 8);
            bf16x8 k1 = *(const bf16x8*)(kb + (ks + 1) * 512 + lane * 8);
            Sa = __builtin_amdgcn_mfma_f32_32x32x16_bf16(k0, qf[ks], Sa, 0, 0, 0);
            Sb = __builtin_amdgcn_mfma_f32_32x32x16_bf16(k1, qf[ks + 1], Sb, 0, 0, 0);
        }
        // mbias broadcast loads AFTER QK (keeps during-QK VGPR live-set low
        // enough for the dual chains; L1-hot). Own reg r needs
        // m = (r&3) + 8*(r>>2) + 4h -> rows m0+4h+{0,8,16,24}.
        const float* mrow = mb_base + m0 + 4 * h;
        float4 mbv0 = *(const float4*)(mrow);
        float4 mbv1 = *(const float4*)(mrow + 8);
        float4 mbv2 = *(const float4*)(mrow + 16);
        float4 mbv3 = *(const float4*)(mrow + 24);
        // P^T = exp(Sa + Sb + mdot), packed to bf16 pairs entirely in regs.
        u32x2 own[4];      // own[g] = bf16 pair-pack of regs r=4g..4g+3
        #pragma unroll
        for (int g = 0; g < 4; ++g) {
            float4 mbv = (g == 0) ? mbv0 : (g == 1) ? mbv1 : (g == 2) ? mbv2 : mbv3;
            bf16x4 tq;
            #pragma unroll
            for (int q = 0; q < 4; ++q) {
                float v = Sa[g * 4 + q] + Sb[g * 4 + q] +
                          ((q == 0) ? mbv.x : (q == 1) ? mbv.y : (q == 2) ? mbv.z : mbv.w);
                mmax = fmaxf(mmax, v);
                float e = __expf(v);
                lsum += e;
                tq[q] = (bf16_t)e;
            }
            own[g] = __builtin_bit_cast(u32x2, tq);
        }
        // PV: O^T += V^T . P^T. B-frag (elem e) of lane (c,h) needs
        // m = 16ks + 8h + e: elems 0-3 from half 0, 4-7 from half 1, both at
        // regs r = 4*(2ks+h)+q of lane (c, e>>2) -> lane i<->i+32 exchange.
        #pragma unroll
        for (int ks = 0; ks < 2; ++ks) {
            unsigned oAlo = own[2 * ks].x,     oAhi = own[2 * ks].y;      // g=2ks
            unsigned oBlo = own[2 * ks + 1].x, oBhi = own[2 * ks + 1].y;  // g=2ks+1
            unsigned slo = h ? oAlo : oBlo;    // send group 2ks+(1-h)
            unsigned shi = h ? oAhi : oBhi;
            unsigned rlo = (unsigned)__shfl_xor((int)slo, 32, 64);
            unsigned rhi = (unsigned)__shfl_xor((int)shi, 32, 64);
            unsigned mlo = h ? oBlo : oAlo;    // my group 2ks+h
            unsigned mhi = h ? oBhi : oAhi;
            u32x4 uu;
            uu.x = h ? rlo : mlo;              // elems 0-3 (from half 0)
            uu.y = h ? rhi : mhi;
            uu.z = h ? mlo : rlo;              // elems 4-7 (from half 1)
            uu.w = h ? mhi : rhi;
            bf16x8 pb = __builtin_bit_cast(bf16x8, uu);
            #pragma unroll
            for (int dt = 0; dt < 8; ++dt) {
                bf16x8 vv = *(const bf16x8*)(vb + (ks * 8 + dt) * 512 + lane * 8);
                oaccT[dt] = __builtin_amdgcn_mfma_f32_32x32x16_bf16(vv, pb, oaccT[dt], 0, 0, 0);
            }
        }
    }
    #undef STAGE

    // ---- pair-combine epilogue: grp1 dumps, grp0 accumulates + stores ------
    __syncthreads();                       // (a) all PV reads of bufs done
    if (grp == 1) {
        float* dst = (float*)(smem + gw * 32768);
        #pragma unroll
        for (int dt = 0; dt < 8; ++dt) {
            #pragma unroll
            for (int q = 0; q < 4; ++q) {
                float4 v4;
                v4.x = oaccT[dt][q * 4 + 0]; v4.y = oaccT[dt][q * 4 + 1];
                v4.z = oaccT[dt][q * 4 + 2]; v4.w = oaccT[dt][q * 4 + 3];
                *(float4*)(dst + dt * 1024 + q * 256 + lane * 4) = v4;
            }
        }
        float* aux = (float*)(smem + 131072 + gw * 512);
        aux[lane] = lsum;
        aux[64 + lane] = mmax;
    }
    __syncthreads();                       // (b) dumps visible
    if (grp == 0) {
        const float* src = (const float*)(smem + gw * 32768);
        #pragma unroll
        for (int dt = 0; dt < 8; ++dt) {
            #pragma unroll
            for (int q = 0; q < 4; ++q) {
                float4 v4 = *(const float4*)(src + dt * 1024 + q * 256 + lane * 4);
                oaccT[dt][q * 4 + 0] += v4.x; oaccT[dt][q * 4 + 1] += v4.y;
                oaccT[dt][q * 4 + 2] += v4.z; oaccT[dt][q * 4 + 3] += v4.w;
            }
        }
        const float* aux = (const float*)(smem + 131072 + gw * 512);
        lsum += aux[lane];
        mmax = fmaxf(mmax, aux[64 + lane]);
    }
    __syncthreads();                       // (c) combine reads done before patch
    if (grp == 0) {
        // l-sum / row-max finalize (per-lane over m, + h-half merge)
        mmax = fmaxf(mmax, __shfl_xor(mmax, 32, 64));
        lsum += __shfl_xor(lsum, 32, 64);
        if (lane < 32) {
            int row = b * NL + l0 + gw * 32 + lane;
            ws_l[half * (NB * NL) + row] = lsum;
            ws_m[half * (NB * NL) + row] = mmax;
        }
        // epilogue: O^T -> coalesced O via per-wave LDS patch. FULLY
        // UNROLLED: oaccT must only ever be indexed by compile-time constants
        // or it is demoted to scratch.
        float* patch = (float*)(smem + gw * 4352);   // [32 d][stride 33] floats
        float* oseg = out + (size_t)(b * NL + l0 + gw * 32) * OUTW + ND * (1 + half);
        #pragma unroll
        for (int dt = 0; dt < 8; ++dt) {
            asm volatile("s_waitcnt lgkmcnt(0)" ::: "memory");
            #pragma unroll
            for (int r = 0; r < 16; ++r)
                patch[((r & 3) + 8 * (r >> 2) + 4 * h) * 33 + c] = oaccT[dt][r];
            asm volatile("s_waitcnt lgkmcnt(0)" ::: "memory");
            #pragma unroll
            for (int rr = 0; rr < 16; ++rr) {
                float val = patch[c * 33 + rr * 2 + h];
                oseg[(size_t)(rr * 2 + h) * OUTW + dt * 32 + c] = val;
            }
        }
    }
}

// ---- Kernel C: output_two numerator/denominator (no separate softmax) ------
// grid 256 = b*32 + slice; LDS pre-reduce cuts ws_num atomics 4x.
__global__ __launch_bounds__(256) void o2_kernel(
    const float* __restrict__ input, const float* __restrict__ ws_idot,
    const float* __restrict__ ws_m, float* __restrict__ ws_num,
    float* __restrict__ ws_den)
{
    __shared__ float4 red[256];
    int b = blockIdx.x >> 5, slice = blockIdx.x & 31;
    int t = threadIdx.x;
    int lgrp = t >> 6, d4 = (t & 63) * 4;
    float4 acc = {0.f, 0.f, 0.f, 0.f};
    float esum = 0.f;
    for (int i = 0; i < 16; ++i) {
        int row = b * NL + slice * 64 + lgrp * 16 + i;
        float e = __expf(ws_idot[row] + fmaxf(ws_m[row], ws_m[NB * NL + row]));
        float4 v = *(const float4*)(input + (size_t)row * ND + d4);
        acc.x += e * v.x; acc.y += e * v.y;
        acc.z += e * v.z; acc.w += e * v.w;
        esum += e;
    }
    red[t] = acc;
    __syncthreads();
    if (t < 64) {
        float4 a0 = red[t], a1 = red[t + 64], a2 = red[t + 128], a3 = red[t + 192];
        float* dst = ws_num + b * ND + t * 4;
        atomicAdd(dst + 0, a0.x + a1.x + a2.x + a3.x);
        atomicAdd(dst + 1, a0.y + a1.y + a2.y + a3.y);
        atomicAdd(dst + 2, a0.z + a1.z + a2.z + a3.z);
        atomicAdd(dst + 3, a0.w + a1.w + a2.w + a3.w);
    }
    if ((t & 63) == 0) atomicAdd(ws_den + b, esum);
}

// ---- Kernel D: combine halves + assemble all 4 output segments -------------
__global__ __launch_bounds__(256) void assembly_kernel(
    const float* __restrict__ input, const float* __restrict__ ws_num,
    const float* __restrict__ ws_den, const float* __restrict__ ws_l,
    float* __restrict__ out)
{
    size_t tid = (size_t)blockIdx.x * 256 + threadIdx.x;
    size_t row = tid >> 6;
    int d = (int)(tid & 63) * 4;
    int b = (int)(row >> 11);
    float inv  = 1.0f / (ws_l[row] + ws_l[NB * NL + row]);
    float dinv = 1.0f / ws_den[b];
    float* po = out + row * OUTW;
    float4 in = *(const float4*)(input + row * ND + d);
    float4 pa = *(const float4*)(po + ND + d);
    float4 pb = *(const float4*)(po + 2 * ND + d);
    float4 nu = *(const float4*)(ws_num + b * ND + d);
    float4 o1;
    o1.x = (pa.x + pb.x) * inv; o1.y = (pa.y + pb.y) * inv;
    o1.z = (pa.z + pb.z) * inv; o1.w = (pa.w + pb.w) * inv;
    float4 o2v;
    o2v.x = nu.x * dinv; o2v.y = nu.y * dinv;
    o2v.z = nu.z * dinv; o2v.w = nu.w * dinv;
    *(float4*)(po + d) = in;
    *(float4*)(po + ND + d) = o1;
    float4 q;
    q.x = in.x * o1.x; q.y = in.y * o1.y; q.z = in.z * o1.z; q.w = in.w * o1.w;
    *(float4*)(po + 2 * ND + d) = q;
    float4 r;
    r.x = o2v.x * o1.x; r.y = o2v.y * o1.y; r.z = o2v.z * o1.z; r.w = o2v.w * o1.w;
    *(float4*)(po + 3 * ND + d) = r;
}

// ---- launcher ---------------------------------------------------------------
extern "C" void kernel_launch(void* const* d_in, const int* in_sizes, int n_in,
                              void* d_out, int out_size, void* d_ws, size_t ws_size,
                              hipStream_t stream) {
    const float* input     = (const float*)d_in[0];
    const float* memory    = (const float*)d_in[1];
    const float* mask      = (const float*)d_in[2];
    const float* w_input   = (const float*)d_in[3];
    const float* w_memory  = (const float*)d_in[4];
    const float* dot_scale = (const float*)d_in[5];
    float* out = (float*)d_out;
    char* outc = (char*)d_out;
    float* ws  = (float*)d_ws;

    // ws floats: idot 16K | mbias 16K | l 2x16K | m 2x16K | num 2K | den 8
    float* ws_idot  = ws;
    float* ws_mbias = ws + 16384;
    float* ws_l     = ws + 32768;
    float* ws_m     = ws + 65536;
    float* ws_num   = ws + 98304;
    float* ws_den   = ws + 100352;

    prep_kernel<<<512, 256, 0, stream>>>(memory, mask, w_memory, ws_mbias,
                                         ws_num, outc);
    flash_kernel<<<256, 512, FLASH_LDS, stream>>>(input, dot_scale, w_input,
                                                  ws_mbias, outc, out,
                                                  ws_l, ws_m, ws_idot);
    o2_kernel<<<256, 256, 0, stream>>>(input, ws_idot, ws_m, ws_num, ws_den);
    assembly_kernel<<<4096, 256, 0, stream>>>(input, ws_num, ws_den, ws_l, out);
}

// Round 12
// 193.314 us; speedup vs baseline: 1.1687x; 1.0663x over previous
//
#include <hip/hip_runtime.h>
#include <hip/hip_bf16.h>

// BiAttention, round 14 = EXACT RESTORE of round 9 (best measured state:
// flash 68.4us, total 190.9us). Post-mortem ledger of structural bets since:
//   r10 K-ring/vmcnt(4): null (__syncthreads emits vmcnt(0); drain was cheap)
//   r11 QK(it+1)/PV(it) overlap: VGPR spill (FETCH/WRITE +15MB, 70->89us)
//   r12 barrier-domain split + atomic combine: +28MB RMW traffic (70->102us)
//   r13 dual-S chains: spill again (WRITE 48->53.6MB, 68->83us)
// Diagnosis: qf(64 VGPR) + oaccT(128 AGPR) leave ~60 VGPRs headroom; ANY
// added live state spills (VGPR_Count stays 128 by launch_bounds; spill shows
// as FETCH/WRITE growth). This structure is at its register-constrained
// optimum; r9 is the measured best configuration of it.
// r9 = frag-major K copy (coalesced 1KB dma16), in-register P repack
// (lane i<->i+32 shfl_xor), mbias broadcast loads, fused idot, no setprio.

typedef __bf16 bf16_t;
typedef bf16_t bf16x4 __attribute__((ext_vector_type(4)));
typedef bf16_t bf16x8 __attribute__((ext_vector_type(8)));
typedef float  f32x16 __attribute__((ext_vector_type(16)));
typedef unsigned int u32x2 __attribute__((ext_vector_type(2)));
typedef unsigned int u32x4 __attribute__((ext_vector_type(4)));

#define NB 8
#define NL 2048
#define NM 2048
#define ND 256
#define OUTW 1024
#define MT 64               // m per block-iteration (2 x 32 subtiles)
#define MH 1024
#define NIT 16              // MH/MT
#define LT 128
#define MEMT_X0 8388608u    // byte offset of transposed bf16 V copy in seg0 space
#define FLASH_LDS 133120    // 2x64KB kv dbuf + 2KB epilogue aux

// seg0 byte-space map: flat byte x -> out byte offset. 1KB chunks of x map to
// 4KB-strided rows of out. Any offset added AFTER omap must not cross a 1KB
// chunk in x-space; chunk steps must be added as multiples of 4096.
__device__ __forceinline__ unsigned omap(unsigned x) {
    return ((x >> 10) << 12) | (x & 1023u);
}

__device__ __forceinline__ void dma16(const void* g, void* l) {
    __builtin_amdgcn_global_load_lds(
        (const __attribute__((address_space(1))) unsigned int*)g,
        (__attribute__((address_space(3))) unsigned int*)l, 16, 0, 0);
}

// ---- Kernel A: mbias + bf16 copies (K fragment-major & V transposed) -------
// grid: 8 b * 64 chunks-of-32m = 512 blocks; 256 thr = 4 waves.
// Block 0 additionally zeroes ws_num/ws_den (consumed by o2 after flash).
__global__ __launch_bounds__(256) void prep_kernel(
    const float* __restrict__ memory, const float* __restrict__ mask,
    const float* __restrict__ w_memory,
    float* __restrict__ ws_mbias, float* __restrict__ ws_numden,
    char* __restrict__ outc)
{
    // rows m (32), cols d (256), row stride 264 (+8 pad: frag-emit read 4-way)
    __shared__ __align__(16) bf16_t lds[32 * 264];

    int b  = blockIdx.x >> 6;
    int mc = blockIdx.x & 63;            // 32-m chunk
    int t  = threadIdx.x, w = t >> 6, lane = t & 63;

    if (blockIdx.x == 0) {               // zero ws_num (2048) + ws_den (8)
        for (int k = t; k < 2056; k += 256) ws_numden[k] = 0.f;
    }

    float4 wv = *(const float4*)(w_memory + lane * 4);

    #pragma unroll
    for (int it = 0; it < 8; ++it) {
        int rloc = it * 4 + w;                       // 0..31
        int row  = b * NM + mc * 32 + rloc;          // global memory row
        float4 v = *(const float4*)(memory + (size_t)row * ND + lane * 4);
        float s = v.x * wv.x + v.y * wv.y + v.z * wv.z + v.w * wv.w;
        #pragma unroll
        for (int off = 1; off < 64; off <<= 1) s += __shfl_xor(s, off, 64);
        if (lane == 0) ws_mbias[row] = s - 1e30f * (1.0f - mask[row]);
        bf16x4 bv;
        bv[0] = (bf16_t)v.x; bv[1] = (bf16_t)v.y;
        bv[2] = (bf16_t)v.z; bv[3] = (bf16_t)v.w;
        // stage into LDS (K-frag emit + V-transpose emit both read from here)
        *(bf16x4*)(&lds[rloc * 264 + lane * 4]) = bv;
    }
    __syncthreads();

    // K fragment-major emit: 16KB chunk per (b,mc). Byte o of chunk decomposes
    // as ks=o>>10, h=(o>>9)&1, c=(o>>4)&31, e=o&15: holds K[m=mc*32+c]
    // [d=16ks+8h+e/2]. Thread t writes 4 coalesced 16B granules (r=0..3):
    // o = r*4096 + t*16 -> ks=4r+(t>>6), h=(t>>5)&1, c=t&31.
    {
        unsigned xbase = ((unsigned)(b * 64 + mc)) * 16384u;
        int c = t & 31, h5 = (t >> 5) & 1, ksh = t >> 6;
        #pragma unroll
        for (int r = 0; r < 4; ++r) {
            bf16x8 g = *(const bf16x8*)(&lds[c * 264 + (4 * r + ksh) * 16 + h5 * 8]);
            *(bf16x8*)(outc + omap(xbase + r * 4096u + (unsigned)t * 16u)) = g;
        }
    }

    // transposed V emit: layout [b][m>>3][d][m&7]; thread t = d column.
    int d = t;
    #pragma unroll
    for (int mc4 = 0; mc4 < 4; ++mc4) {
        bf16x8 pk;
        #pragma unroll
        for (int j = 0; j < 8; ++j) pk[j] = lds[(mc4 * 8 + j) * 264 + d];
        unsigned x = MEMT_X0 +
            2u * ((((unsigned)(b * 256 + mc * 4 + mc4)) * ND + d) * 8);
        *(bf16x8*)(outc + omap(x)) = pk;   // 16B granule, in-chunk ✓
    }
}

// ---- Kernel B: flash attention partials (+ fused idot) ---------------------
// grid 256 = lt*16 + b*2 + half; 8 waves; wave w: gw=w&3 owns L rows
// [gw*32, gw*32+32), grp=w>>2 owns m-subtile grp of each 64-m tile.
__global__ __launch_bounds__(512, 2) void flash_kernel(
    const float* __restrict__ input, const float* __restrict__ dot_scale,
    const float* __restrict__ w_input, const float* __restrict__ ws_mbias,
    const char* __restrict__ outc, float* __restrict__ out,
    float* __restrict__ ws_l, float* __restrict__ ws_m,
    float* __restrict__ ws_idot)
{
    extern __shared__ __align__(16) char smem[];
    // buf0 [0,65536): K_A|K_B|V_A|V_B (16KB each)
    // buf1 [65536,131072): same layout
    // aux  [131072,133120): 4 gw x 512B epilogue lsum/mmax exchange

    int bid = blockIdx.x;
    int half = bid & 1, b = (bid >> 1) & 7, lt = bid >> 4;
    int l0 = lt * LT;
    int m_base = half * MH;
    int t = threadIdx.x, w = t >> 6, lane = t & 63;
    int gw = w & 3, grp = w >> 2;
    int c = lane & 31, h = lane >> 5;

    // Q fragments in registers (B-operand; col = lane&31 = l, k contiguous d)
    // Fused idot: sum unscaled Q row against w_input while it's in registers.
    const float* qrow = input + (size_t)(b * NL + l0 + gw * 32 + c) * ND;
    bool do_idot = (half == 0) && (grp == 0);
    float idot_s = 0.f;
    bf16x8 qf[16];
    #pragma unroll
    for (int ks = 0; ks < 16; ++ks) {
        int d0 = ks * 16 + h * 8;
        float4 a0 = *(const float4*)(qrow + d0);
        float4 a1 = *(const float4*)(qrow + d0 + 4);
        float4 s0 = *(const float4*)(dot_scale + d0);
        float4 s1 = *(const float4*)(dot_scale + d0 + 4);
        if (do_idot) {
            float4 w0 = *(const float4*)(w_input + d0);
            float4 w1 = *(const float4*)(w_input + d0 + 4);
            idot_s += a0.x * w0.x + a0.y * w0.y + a0.z * w0.z + a0.w * w0.w
                    + a1.x * w1.x + a1.y * w1.y + a1.z * w1.z + a1.w * w1.w;
        }
        qf[ks][0] = (bf16_t)(a0.x * s0.x); qf[ks][1] = (bf16_t)(a0.y * s0.y);
        qf[ks][2] = (bf16_t)(a0.z * s0.z); qf[ks][3] = (bf16_t)(a0.w * s0.w);
        qf[ks][4] = (bf16_t)(a1.x * s1.x); qf[ks][5] = (bf16_t)(a1.y * s1.y);
        qf[ks][6] = (bf16_t)(a1.z * s1.z); qf[ks][7] = (bf16_t)(a1.w * s1.w);
    }
    if (do_idot) {
        idot_s += __shfl_xor(idot_s, 32, 64);
        if (lane < 32) ws_idot[b * NL + l0 + gw * 32 + lane] = idot_s;
    }

    // Per-lane DMA source bases (mapped through omap once; later increments
    // stay within-chunk or step whole chunks by multiples of 4096).
    // K fragment-major: chunk (b*64 + half*32 + it*2 + grp), granule i*1024 +
    // lane*16 -> contiguous 1KB per dma16 instruction.
    unsigned xk = ((unsigned)(b * 64 + half * 32 + grp)) * 16384u + (unsigned)lane * 16u;
    const char* kg = outc + omap(xk);
    unsigned xv = MEMT_X0 +
        2u * ((((unsigned)(b * 256 + (m_base >> 3) + grp * 4 + h)) * ND + c) * 8);
    const char* vg = outc + omap(xv);

    char* buf0 = smem;
    char* buf1 = smem + 65536;

    // Each grp's 4 waves cooperatively stage that grp's 16KB K + 16KB V
    // subtile; per-iteration advance 64 m = 32KB x-step -> out step 131072.
    #define STAGE(nbuf) do {                                                  \
        _Pragma("unroll")                                                     \
        for (int j = 0; j < 4; ++j) {                                         \
            int i = gw * 4 + j;                                               \
            int ks = i >> 3, dt = i & 7;                                      \
            dma16(kg + i * 4096, (nbuf) + grp * 16384 + i * 1024);            \
            dma16(vg + ks * 32768 + (dt >> 1) * 4096 + (dt & 1) * 512,        \
                  (nbuf) + 32768 + grp * 16384 + i * 1024);                   \
        }                                                                     \
        kg += 131072; vg += 131072; } while (0)

    // prologue: stage tile 0 into buf0
    STAGE(buf0);

    f32x16 oaccT[8];
    #pragma unroll
    for (int i = 0; i < 8; ++i)
        #pragma unroll
        for (int r = 0; r < 16; ++r) oaccT[i][r] = 0.f;
    float lsum = 0.f, mmax = -3e38f;

    const float* mb_base = ws_mbias + b * NM;

    #pragma unroll 1
    for (int it = 0; it < NIT; ++it) {
        int m0 = m_base + it * MT + grp * 32;
        asm volatile("s_waitcnt vmcnt(0)" ::: "memory"); // my DMA for cur done
        __syncthreads();                                  // all waves' DMA visible
        const char* cb = (it & 1) ? buf1 : buf0;
        char* nb = (it & 1) ? buf0 : buf1;
        const bf16_t* kb = (const bf16_t*)(cb + grp * 16384);
        const bf16_t* vb = (const bf16_t*)(cb + 32768 + grp * 16384);
        if (it + 1 < NIT) {   // stage next tile (safe: barrier above)
            STAGE(nb);
        }
        // mbias for my 32-m subtile: 4 broadcast float4 loads (L1-hot).
        // Own reg r needs m = (r&3) + 8*(r>>2) + 4h -> row m0+4h+8g+q.
        const float* mrow = mb_base + m0 + 4 * h;
        float4 mbv0 = *(const float4*)(mrow);
        float4 mbv1 = *(const float4*)(mrow + 8);
        float4 mbv2 = *(const float4*)(mrow + 16);
        float4 mbv3 = *(const float4*)(mrow + 24);
        // QK: S^T = K . Q^T
        f32x16 S;
        #pragma unroll
        for (int r = 0; r < 16; ++r) S[r] = 0.f;
        #pragma unroll
        for (int ks = 0; ks < 16; ++ks) {
            bf16x8 k0 = *(const bf16x8*)(kb + ks * 512 + lane * 8);
            S = __builtin_amdgcn_mfma_f32_32x32x16_bf16(k0, qf[ks], S, 0, 0, 0);
        }
        // P^T = exp(S^T + mdot), packed to bf16 pairs entirely in registers.
        u32x2 own[4];      // own[g] = bf16 pair-pack of regs r=4g..4g+3
        #pragma unroll
        for (int g = 0; g < 4; ++g) {
            float4 mbv = (g == 0) ? mbv0 : (g == 1) ? mbv1 : (g == 2) ? mbv2 : mbv3;
            bf16x4 tq;
            #pragma unroll
            for (int q = 0; q < 4; ++q) {
                float v = S[g * 4 + q] +
                          ((q == 0) ? mbv.x : (q == 1) ? mbv.y : (q == 2) ? mbv.z : mbv.w);
                mmax = fmaxf(mmax, v);
                float e = __expf(v);
                lsum += e;
                tq[q] = (bf16_t)e;
            }
            own[g] = __builtin_bit_cast(u32x2, tq);
        }
        // PV: O^T += V^T . P^T. B-frag (elem e) of lane (c,h) needs
        // m = 16ks + 8h + e: elems 0-3 from half 0, 4-7 from half 1, both at
        // regs r = 4*(2ks+h)+q of lane (c, e>>2) -> lane i<->i+32 exchange.
        #pragma unroll
        for (int ks = 0; ks < 2; ++ks) {
            unsigned oAlo = own[2 * ks].x,     oAhi = own[2 * ks].y;      // g=2ks
            unsigned oBlo = own[2 * ks + 1].x, oBhi = own[2 * ks + 1].y;  // g=2ks+1
            unsigned slo = h ? oAlo : oBlo;    // send group 2ks+(1-h)
            unsigned shi = h ? oAhi : oBhi;
            unsigned rlo = (unsigned)__shfl_xor((int)slo, 32, 64);
            unsigned rhi = (unsigned)__shfl_xor((int)shi, 32, 64);
            unsigned mlo = h ? oBlo : oAlo;    // my group 2ks+h
            unsigned mhi = h ? oBhi : oAhi;
            u32x4 uu;
            uu.x = h ? rlo : mlo;              // elems 0-3 (from half 0)
            uu.y = h ? rhi : mhi;
            uu.z = h ? mlo : rlo;              // elems 4-7 (from half 1)
            uu.w = h ? mhi : rhi;
            bf16x8 pb = __builtin_bit_cast(bf16x8, uu);
            #pragma unroll
            for (int dt = 0; dt < 8; ++dt) {
                bf16x8 vv = *(const bf16x8*)(vb + (ks * 8 + dt) * 512 + lane * 8);
                oaccT[dt] = __builtin_amdgcn_mfma_f32_32x32x16_bf16(vv, pb, oaccT[dt], 0, 0, 0);
            }
        }
    }
    #undef STAGE

    // ---- pair-combine epilogue: grp1 dumps, grp0 accumulates + stores ------
    __syncthreads();                       // (a) all PV reads of bufs done
    if (grp == 1) {
        float* dst = (float*)(smem + gw * 32768);
        #pragma unroll
        for (int dt = 0; dt < 8; ++dt) {
            #pragma unroll
            for (int q = 0; q < 4; ++q) {
                float4 v4;
                v4.x = oaccT[dt][q * 4 + 0]; v4.y = oaccT[dt][q * 4 + 1];
                v4.z = oaccT[dt][q * 4 + 2]; v4.w = oaccT[dt][q * 4 + 3];
                *(float4*)(dst + dt * 1024 + q * 256 + lane * 4) = v4;
            }
        }
        float* aux = (float*)(smem + 131072 + gw * 512);
        aux[lane] = lsum;
        aux[64 + lane] = mmax;
    }
    __syncthreads();                       // (b) dumps visible
    if (grp == 0) {
        const float* src = (const float*)(smem + gw * 32768);
        #pragma unroll
        for (int dt = 0; dt < 8; ++dt) {
            #pragma unroll
            for (int q = 0; q < 4; ++q) {
                float4 v4 = *(const float4*)(src + dt * 1024 + q * 256 + lane * 4);
                oaccT[dt][q * 4 + 0] += v4.x; oaccT[dt][q * 4 + 1] += v4.y;
                oaccT[dt][q * 4 + 2] += v4.z; oaccT[dt][q * 4 + 3] += v4.w;
            }
        }
        const float* aux = (const float*)(smem + 131072 + gw * 512);
        lsum += aux[lane];
        mmax = fmaxf(mmax, aux[64 + lane]);
    }
    __syncthreads();                       // (c) combine reads done before patch
    if (grp == 0) {
        // l-sum / row-max finalize (per-lane over m, + h-half merge)
        mmax = fmaxf(mmax, __shfl_xor(mmax, 32, 64));
        lsum += __shfl_xor(lsum, 32, 64);
        if (lane < 32) {
            int row = b * NL + l0 + gw * 32 + lane;
            ws_l[half * (NB * NL) + row] = lsum;
            ws_m[half * (NB * NL) + row] = mmax;
        }
        // epilogue: O^T -> coalesced O via per-wave LDS patch. FULLY
        // UNROLLED: oaccT must only ever be indexed by compile-time constants
        // or it is demoted to scratch.
        float* patch = (float*)(smem + gw * 4352);   // [32 d][stride 33] floats
        float* oseg = out + (size_t)(b * NL + l0 + gw * 32) * OUTW + ND * (1 + half);
        #pragma unroll
        for (int dt = 0; dt < 8; ++dt) {
            asm volatile("s_waitcnt lgkmcnt(0)" ::: "memory");
            #pragma unroll
            for (int r = 0; r < 16; ++r)
                patch[((r & 3) + 8 * (r >> 2) + 4 * h) * 33 + c] = oaccT[dt][r];
            asm volatile("s_waitcnt lgkmcnt(0)" ::: "memory");
            #pragma unroll
            for (int rr = 0; rr < 16; ++rr) {
                float val = patch[c * 33 + rr * 2 + h];
                oseg[(size_t)(rr * 2 + h) * OUTW + dt * 32 + c] = val;
            }
        }
    }
}

// ---- Kernel C: output_two numerator/denominator (no separate softmax) ------
// grid 256 = b*32 + slice; LDS pre-reduce cuts ws_num atomics 4x.
__global__ __launch_bounds__(256) void o2_kernel(
    const float* __restrict__ input, const float* __restrict__ ws_idot,
    const float* __restrict__ ws_m, float* __restrict__ ws_num,
    float* __restrict__ ws_den)
{
    __shared__ float4 red[256];
    int b = blockIdx.x >> 5, slice = blockIdx.x & 31;
    int t = threadIdx.x;
    int lgrp = t >> 6, d4 = (t & 63) * 4;
    float4 acc = {0.f, 0.f, 0.f, 0.f};
    float esum = 0.f;
    for (int i = 0; i < 16; ++i) {
        int row = b * NL + slice * 64 + lgrp * 16 + i;
        float e = __expf(ws_idot[row] + fmaxf(ws_m[row], ws_m[NB * NL + row]));
        float4 v = *(const float4*)(input + (size_t)row * ND + d4);
        acc.x += e * v.x; acc.y += e * v.y;
        acc.z += e * v.z; acc.w += e * v.w;
        esum += e;
    }
    red[t] = acc;
    __syncthreads();
    if (t < 64) {
        float4 a0 = red[t], a1 = red[t + 64], a2 = red[t + 128], a3 = red[t + 192];
        float* dst = ws_num + b * ND + t * 4;
        atomicAdd(dst + 0, a0.x + a1.x + a2.x + a3.x);
        atomicAdd(dst + 1, a0.y + a1.y + a2.y + a3.y);
        atomicAdd(dst + 2, a0.z + a1.z + a2.z + a3.z);
        atomicAdd(dst + 3, a0.w + a1.w + a2.w + a3.w);
    }
    if ((t & 63) == 0) atomicAdd(ws_den + b, esum);
}

// ---- Kernel D: combine halves + assemble all 4 output segments -------------
__global__ __launch_bounds__(256) void assembly_kernel(
    const float* __restrict__ input, const float* __restrict__ ws_num,
    const float* __restrict__ ws_den, const float* __restrict__ ws_l,
    float* __restrict__ out)
{
    size_t tid = (size_t)blockIdx.x * 256 + threadIdx.x;
    size_t row = tid >> 6;
    int d = (int)(tid & 63) * 4;
    int b = (int)(row >> 11);
    float inv  = 1.0f / (ws_l[row] + ws_l[NB * NL + row]);
    float dinv = 1.0f / ws_den[b];
    float* po = out + row * OUTW;
    float4 in = *(const float4*)(input + row * ND + d);
    float4 pa = *(const float4*)(po + ND + d);
    float4 pb = *(const float4*)(po + 2 * ND + d);
    float4 nu = *(const float4*)(ws_num + b * ND + d);
    float4 o1;
    o1.x = (pa.x + pb.x) * inv; o1.y = (pa.y + pb.y) * inv;
    o1.z = (pa.z + pb.z) * inv; o1.w = (pa.w + pb.w) * inv;
    float4 o2v;
    o2v.x = nu.x * dinv; o2v.y = nu.y * dinv;
    o2v.z = nu.z * dinv; o2v.w = nu.w * dinv;
    *(float4*)(po + d) = in;
    *(float4*)(po + ND + d) = o1;
    float4 q;
    q.x = in.x * o1.x; q.y = in.y * o1.y; q.z = in.z * o1.z; q.w = in.w * o1.w;
    *(float4*)(po + 2 * ND + d) = q;
    float4 r;
    r.x = o2v.x * o1.x; r.y = o2v.y * o1.y; r.z = o2v.z * o1.z; r.w = o2v.w * o1.w;
    *(float4*)(po + 3 * ND + d) = r;
}

// ---- launcher ---------------------------------------------------------------
extern "C" void kernel_launch(void* const* d_in, const int* in_sizes, int n_in,
                              void* d_out, int out_size, void* d_ws, size_t ws_size,
                              hipStream_t stream) {
    const float* input     = (const float*)d_in[0];
    const float* memory    = (const float*)d_in[1];
    const float* mask      = (const float*)d_in[2];
    const float* w_input   = (const float*)d_in[3];
    const float* w_memory  = (const float*)d_in[4];
    const float* dot_scale = (const float*)d_in[5];
    float* out = (float*)d_out;
    char* outc = (char*)d_out;
    float* ws  = (float*)d_ws;

    // ws floats: idot 16K | mbias 16K | l 2x16K | m 2x16K | num 2K | den 8
    float* ws_idot  = ws;
    float* ws_mbias = ws + 16384;
    float* ws_l     = ws + 32768;
    float* ws_m     = ws + 65536;
    float* ws_num   = ws + 98304;
    float* ws_den   = ws + 100352;

    prep_kernel<<<512, 256, 0, stream>>>(memory, mask, w_memory, ws_mbias,
                                         ws_num, outc);
    flash_kernel<<<256, 512, FLASH_LDS, stream>>>(input, dot_scale, w_input,
                                                  ws_mbias, outc, out,
                                                  ws_l, ws_m, ws_idot);
    o2_kernel<<<256, 256, 0, stream>>>(input, ws_idot, ws_m, ws_num, ws_den);
    assembly_kernel<<<4096, 256, 0, stream>>>(input, ws_num, ws_den, ws_l, out);
}

// Round 13
// 188.560 us; speedup vs baseline: 1.1982x; 1.0252x over previous
//
#include <hip/hip_runtime.h>
#include <hip/hip_bf16.h>

// BiAttention, round 15 = TERMINAL: hold round 9/14 (best measured state:
// 190.9us total best, 193.3 reproduced; entry baseline was 204-205us).
//
// Session ledger (all counter-verified):
//   WINS: 8-wave occupancy split (95.7->69us flash), fused idot (-1 dispatch,
//     -16.8MB reads), frag-major K copy (gather->contiguous 1KB dma16),
//     in-register P repack (P-LDS round-trip + fence removed).
//   FALSIFIED: r10 K-ring/vmcnt(4) null (syncthreads drains; latency already
//     hidden); r11 QK/PV overlap -> spill (+15MB FETCH/WRITE); r12 barrier
//     split -> +28MB atomic RMW; r13 dual-S -> spill (+5.6MB WRITE).
//   CONSTRAINT: 32L x 256d/wave output => oaccT=128 AGPR; qf=64 VGPR; at
//     launch_bounds(512,2) any added live state spills (spill signature =
//     FETCH/WRITE growth at pinned VGPR_Count=128). Register-constrained
//     optimum of the 32x32-fragment structure. The 16x16-fragment rewrite
//     (only path to 3 waves/SIMD) needs 6 unverified lane-mapping
//     derivations with no partial-credit channel in this harness: -EV.

typedef __bf16 bf16_t;
typedef bf16_t bf16x4 __attribute__((ext_vector_type(4)));
typedef bf16_t bf16x8 __attribute__((ext_vector_type(8)));
typedef float  f32x16 __attribute__((ext_vector_type(16)));
typedef unsigned int u32x2 __attribute__((ext_vector_type(2)));
typedef unsigned int u32x4 __attribute__((ext_vector_type(4)));

#define NB 8
#define NL 2048
#define NM 2048
#define ND 256
#define OUTW 1024
#define MT 64               // m per block-iteration (2 x 32 subtiles)
#define MH 1024
#define NIT 16              // MH/MT
#define LT 128
#define MEMT_X0 8388608u    // byte offset of transposed bf16 V copy in seg0 space
#define FLASH_LDS 133120    // 2x64KB kv dbuf + 2KB epilogue aux

// seg0 byte-space map: flat byte x -> out byte offset. 1KB chunks of x map to
// 4KB-strided rows of out. Any offset added AFTER omap must not cross a 1KB
// chunk in x-space; chunk steps must be added as multiples of 4096.
__device__ __forceinline__ unsigned omap(unsigned x) {
    return ((x >> 10) << 12) | (x & 1023u);
}

__device__ __forceinline__ void dma16(const void* g, void* l) {
    __builtin_amdgcn_global_load_lds(
        (const __attribute__((address_space(1))) unsigned int*)g,
        (__attribute__((address_space(3))) unsigned int*)l, 16, 0, 0);
}

// ---- Kernel A: mbias + bf16 copies (K fragment-major & V transposed) -------
// grid: 8 b * 64 chunks-of-32m = 512 blocks; 256 thr = 4 waves.
// Block 0 additionally zeroes ws_num/ws_den (consumed by o2 after flash).
__global__ __launch_bounds__(256) void prep_kernel(
    const float* __restrict__ memory, const float* __restrict__ mask,
    const float* __restrict__ w_memory,
    float* __restrict__ ws_mbias, float* __restrict__ ws_numden,
    char* __restrict__ outc)
{
    // rows m (32), cols d (256), row stride 264 (+8 pad: frag-emit read 4-way)
    __shared__ __align__(16) bf16_t lds[32 * 264];

    int b  = blockIdx.x >> 6;
    int mc = blockIdx.x & 63;            // 32-m chunk
    int t  = threadIdx.x, w = t >> 6, lane = t & 63;

    if (blockIdx.x == 0) {               // zero ws_num (2048) + ws_den (8)
        for (int k = t; k < 2056; k += 256) ws_numden[k] = 0.f;
    }

    float4 wv = *(const float4*)(w_memory + lane * 4);

    #pragma unroll
    for (int it = 0; it < 8; ++it) {
        int rloc = it * 4 + w;                       // 0..31
        int row  = b * NM + mc * 32 + rloc;          // global memory row
        float4 v = *(const float4*)(memory + (size_t)row * ND + lane * 4);
        float s = v.x * wv.x + v.y * wv.y + v.z * wv.z + v.w * wv.w;
        #pragma unroll
        for (int off = 1; off < 64; off <<= 1) s += __shfl_xor(s, off, 64);
        if (lane == 0) ws_mbias[row] = s - 1e30f * (1.0f - mask[row]);
        bf16x4 bv;
        bv[0] = (bf16_t)v.x; bv[1] = (bf16_t)v.y;
        bv[2] = (bf16_t)v.z; bv[3] = (bf16_t)v.w;
        // stage into LDS (K-frag emit + V-transpose emit both read from here)
        *(bf16x4*)(&lds[rloc * 264 + lane * 4]) = bv;
    }
    __syncthreads();

    // K fragment-major emit: 16KB chunk per (b,mc). Byte o of chunk decomposes
    // as ks=o>>10, h=(o>>9)&1, c=(o>>4)&31, e=o&15: holds K[m=mc*32+c]
    // [d=16ks+8h+e/2]. Thread t writes 4 coalesced 16B granules (r=0..3):
    // o = r*4096 + t*16 -> ks=4r+(t>>6), h=(t>>5)&1, c=t&31.
    {
        unsigned xbase = ((unsigned)(b * 64 + mc)) * 16384u;
        int c = t & 31, h5 = (t >> 5) & 1, ksh = t >> 6;
        #pragma unroll
        for (int r = 0; r < 4; ++r) {
            bf16x8 g = *(const bf16x8*)(&lds[c * 264 + (4 * r + ksh) * 16 + h5 * 8]);
            *(bf16x8*)(outc + omap(xbase + r * 4096u + (unsigned)t * 16u)) = g;
        }
    }

    // transposed V emit: layout [b][m>>3][d][m&7]; thread t = d column.
    int d = t;
    #pragma unroll
    for (int mc4 = 0; mc4 < 4; ++mc4) {
        bf16x8 pk;
        #pragma unroll
        for (int j = 0; j < 8; ++j) pk[j] = lds[(mc4 * 8 + j) * 264 + d];
        unsigned x = MEMT_X0 +
            2u * ((((unsigned)(b * 256 + mc * 4 + mc4)) * ND + d) * 8);
        *(bf16x8*)(outc + omap(x)) = pk;   // 16B granule, in-chunk ✓
    }
}

// ---- Kernel B: flash attention partials (+ fused idot) ---------------------
// grid 256 = lt*16 + b*2 + half; 8 waves; wave w: gw=w&3 owns L rows
// [gw*32, gw*32+32), grp=w>>2 owns m-subtile grp of each 64-m tile.
__global__ __launch_bounds__(512, 2) void flash_kernel(
    const float* __restrict__ input, const float* __restrict__ dot_scale,
    const float* __restrict__ w_input, const float* __restrict__ ws_mbias,
    const char* __restrict__ outc, float* __restrict__ out,
    float* __restrict__ ws_l, float* __restrict__ ws_m,
    float* __restrict__ ws_idot)
{
    extern __shared__ __align__(16) char smem[];
    // buf0 [0,65536): K_A|K_B|V_A|V_B (16KB each)
    // buf1 [65536,131072): same layout
    // aux  [131072,133120): 4 gw x 512B epilogue lsum/mmax exchange

    int bid = blockIdx.x;
    int half = bid & 1, b = (bid >> 1) & 7, lt = bid >> 4;
    int l0 = lt * LT;
    int m_base = half * MH;
    int t = threadIdx.x, w = t >> 6, lane = t & 63;
    int gw = w & 3, grp = w >> 2;
    int c = lane & 31, h = lane >> 5;

    // Q fragments in registers (B-operand; col = lane&31 = l, k contiguous d)
    // Fused idot: sum unscaled Q row against w_input while it's in registers.
    const float* qrow = input + (size_t)(b * NL + l0 + gw * 32 + c) * ND;
    bool do_idot = (half == 0) && (grp == 0);
    float idot_s = 0.f;
    bf16x8 qf[16];
    #pragma unroll
    for (int ks = 0; ks < 16; ++ks) {
        int d0 = ks * 16 + h * 8;
        float4 a0 = *(const float4*)(qrow + d0);
        float4 a1 = *(const float4*)(qrow + d0 + 4);
        float4 s0 = *(const float4*)(dot_scale + d0);
        float4 s1 = *(const float4*)(dot_scale + d0 + 4);
        if (do_idot) {
            float4 w0 = *(const float4*)(w_input + d0);
            float4 w1 = *(const float4*)(w_input + d0 + 4);
            idot_s += a0.x * w0.x + a0.y * w0.y + a0.z * w0.z + a0.w * w0.w
                    + a1.x * w1.x + a1.y * w1.y + a1.z * w1.z + a1.w * w1.w;
        }
        qf[ks][0] = (bf16_t)(a0.x * s0.x); qf[ks][1] = (bf16_t)(a0.y * s0.y);
        qf[ks][2] = (bf16_t)(a0.z * s0.z); qf[ks][3] = (bf16_t)(a0.w * s0.w);
        qf[ks][4] = (bf16_t)(a1.x * s1.x); qf[ks][5] = (bf16_t)(a1.y * s1.y);
        qf[ks][6] = (bf16_t)(a1.z * s1.z); qf[ks][7] = (bf16_t)(a1.w * s1.w);
    }
    if (do_idot) {
        idot_s += __shfl_xor(idot_s, 32, 64);
        if (lane < 32) ws_idot[b * NL + l0 + gw * 32 + lane] = idot_s;
    }

    // Per-lane DMA source bases (mapped through omap once; later increments
    // stay within-chunk or step whole chunks by multiples of 4096).
    // K fragment-major: chunk (b*64 + half*32 + it*2 + grp), granule i*1024 +
    // lane*16 -> contiguous 1KB per dma16 instruction.
    unsigned xk = ((unsigned)(b * 64 + half * 32 + grp)) * 16384u + (unsigned)lane * 16u;
    const char* kg = outc + omap(xk);
    unsigned xv = MEMT_X0 +
        2u * ((((unsigned)(b * 256 + (m_base >> 3) + grp * 4 + h)) * ND + c) * 8);
    const char* vg = outc + omap(xv);

    char* buf0 = smem;
    char* buf1 = smem + 65536;

    // Each grp's 4 waves cooperatively stage that grp's 16KB K + 16KB V
    // subtile; per-iteration advance 64 m = 32KB x-step -> out step 131072.
    #define STAGE(nbuf) do {                                                  \
        _Pragma("unroll")                                                     \
        for (int j = 0; j < 4; ++j) {                                         \
            int i = gw * 4 + j;                                               \
            int ks = i >> 3, dt = i & 7;                                      \
            dma16(kg + i * 4096, (nbuf) + grp * 16384 + i * 1024);            \
            dma16(vg + ks * 32768 + (dt >> 1) * 4096 + (dt & 1) * 512,        \
                  (nbuf) + 32768 + grp * 16384 + i * 1024);                   \
        }                                                                     \
        kg += 131072; vg += 131072; } while (0)

    // prologue: stage tile 0 into buf0
    STAGE(buf0);

    f32x16 oaccT[8];
    #pragma unroll
    for (int i = 0; i < 8; ++i)
        #pragma unroll
        for (int r = 0; r < 16; ++r) oaccT[i][r] = 0.f;
    float lsum = 0.f, mmax = -3e38f;

    const float* mb_base = ws_mbias + b * NM;

    #pragma unroll 1
    for (int it = 0; it < NIT; ++it) {
        int m0 = m_base + it * MT + grp * 32;
        asm volatile("s_waitcnt vmcnt(0)" ::: "memory"); // my DMA for cur done
        __syncthreads();                                  // all waves' DMA visible
        const char* cb = (it & 1) ? buf1 : buf0;
        char* nb = (it & 1) ? buf0 : buf1;
        const bf16_t* kb = (const bf16_t*)(cb + grp * 16384);
        const bf16_t* vb = (const bf16_t*)(cb + 32768 + grp * 16384);
        if (it + 1 < NIT) {   // stage next tile (safe: barrier above)
            STAGE(nb);
        }
        // mbias for my 32-m subtile: 4 broadcast float4 loads (L1-hot).
        // Own reg r needs m = (r&3) + 8*(r>>2) + 4h -> row m0+4h+8g+q.
        const float* mrow = mb_base + m0 + 4 * h;
        float4 mbv0 = *(const float4*)(mrow);
        float4 mbv1 = *(const float4*)(mrow + 8);
        float4 mbv2 = *(const float4*)(mrow + 16);
        float4 mbv3 = *(const float4*)(mrow + 24);
        // QK: S^T = K . Q^T
        f32x16 S;
        #pragma unroll
        for (int r = 0; r < 16; ++r) S[r] = 0.f;
        #pragma unroll
        for (int ks = 0; ks < 16; ++ks) {
            bf16x8 k0 = *(const bf16x8*)(kb + ks * 512 + lane * 8);
            S = __builtin_amdgcn_mfma_f32_32x32x16_bf16(k0, qf[ks], S, 0, 0, 0);
        }
        // P^T = exp(S^T + mdot), packed to bf16 pairs entirely in registers.
        u32x2 own[4];      // own[g] = bf16 pair-pack of regs r=4g..4g+3
        #pragma unroll
        for (int g = 0; g < 4; ++g) {
            float4 mbv = (g == 0) ? mbv0 : (g == 1) ? mbv1 : (g == 2) ? mbv2 : mbv3;
            bf16x4 tq;
            #pragma unroll
            for (int q = 0; q < 4; ++q) {
                float v = S[g * 4 + q] +
                          ((q == 0) ? mbv.x : (q == 1) ? mbv.y : (q == 2) ? mbv.z : mbv.w);
                mmax = fmaxf(mmax, v);
                float e = __expf(v);
                lsum += e;
                tq[q] = (bf16_t)e;
            }
            own[g] = __builtin_bit_cast(u32x2, tq);
        }
        // PV: O^T += V^T . P^T. B-frag (elem e) of lane (c,h) needs
        // m = 16ks + 8h + e: elems 0-3 from half 0, 4-7 from half 1, both at
        // regs r = 4*(2ks+h)+q of lane (c, e>>2) -> lane i<->i+32 exchange.
        #pragma unroll
        for (int ks = 0; ks < 2; ++ks) {
            unsigned oAlo = own[2 * ks].x,     oAhi = own[2 * ks].y;      // g=2ks
            unsigned oBlo = own[2 * ks + 1].x, oBhi = own[2 * ks + 1].y;  // g=2ks+1
            unsigned slo = h ? oAlo : oBlo;    // send group 2ks+(1-h)
            unsigned shi = h ? oAhi : oBhi;
            unsigned rlo = (unsigned)__shfl_xor((int)slo, 32, 64);
            unsigned rhi = (unsigned)__shfl_xor((int)shi, 32, 64);
            unsigned mlo = h ? oBlo : oAlo;    // my group 2ks+h
            unsigned mhi = h ? oBhi : oAhi;
            u32x4 uu;
            uu.x = h ? rlo : mlo;              // elems 0-3 (from half 0)
            uu.y = h ? rhi : mhi;
            uu.z = h ? mlo : rlo;              // elems 4-7 (from half 1)
            uu.w = h ? mhi : rhi;
            bf16x8 pb = __builtin_bit_cast(bf16x8, uu);
            #pragma unroll
            for (int dt = 0; dt < 8; ++dt) {
                bf16x8 vv = *(const bf16x8*)(vb + (ks * 8 + dt) * 512 + lane * 8);
                oaccT[dt] = __builtin_amdgcn_mfma_f32_32x32x16_bf16(vv, pb, oaccT[dt], 0, 0, 0);
            }
        }
    }
    #undef STAGE

    // ---- pair-combine epilogue: grp1 dumps, grp0 accumulates + stores ------
    __syncthreads();                       // (a) all PV reads of bufs done
    if (grp == 1) {
        float* dst = (float*)(smem + gw * 32768);
        #pragma unroll
        for (int dt = 0; dt < 8; ++dt) {
            #pragma unroll
            for (int q = 0; q < 4; ++q) {
                float4 v4;
                v4.x = oaccT[dt][q * 4 + 0]; v4.y = oaccT[dt][q * 4 + 1];
                v4.z = oaccT[dt][q * 4 + 2]; v4.w = oaccT[dt][q * 4 + 3];
                *(float4*)(dst + dt * 1024 + q * 256 + lane * 4) = v4;
            }
        }
        float* aux = (float*)(smem + 131072 + gw * 512);
        aux[lane] = lsum;
        aux[64 + lane] = mmax;
    }
    __syncthreads();                       // (b) dumps visible
    if (grp == 0) {
        const float* src = (const float*)(smem + gw * 32768);
        #pragma unroll
        for (int dt = 0; dt < 8; ++dt) {
            #pragma unroll
            for (int q = 0; q < 4; ++q) {
                float4 v4 = *(const float4*)(src + dt * 1024 + q * 256 + lane * 4);
                oaccT[dt][q * 4 + 0] += v4.x; oaccT[dt][q * 4 + 1] += v4.y;
                oaccT[dt][q * 4 + 2] += v4.z; oaccT[dt][q * 4 + 3] += v4.w;
            }
        }
        const float* aux = (const float*)(smem + 131072 + gw * 512);
        lsum += aux[lane];
        mmax = fmaxf(mmax, aux[64 + lane]);
    }
    __syncthreads();                       // (c) combine reads done before patch
    if (grp == 0) {
        // l-sum / row-max finalize (per-lane over m, + h-half merge)
        mmax = fmaxf(mmax, __shfl_xor(mmax, 32, 64));
        lsum += __shfl_xor(lsum, 32, 64);
        if (lane < 32) {
            int row = b * NL + l0 + gw * 32 + lane;
            ws_l[half * (NB * NL) + row] = lsum;
            ws_m[half * (NB * NL) + row] = mmax;
        }
        // epilogue: O^T -> coalesced O via per-wave LDS patch. FULLY
        // UNROLLED: oaccT must only ever be indexed by compile-time constants
        // or it is demoted to scratch.
        float* patch = (float*)(smem + gw * 4352);   // [32 d][stride 33] floats
        float* oseg = out + (size_t)(b * NL + l0 + gw * 32) * OUTW + ND * (1 + half);
        #pragma unroll
        for (int dt = 0; dt < 8; ++dt) {
            asm volatile("s_waitcnt lgkmcnt(0)" ::: "memory");
            #pragma unroll
            for (int r = 0; r < 16; ++r)
                patch[((r & 3) + 8 * (r >> 2) + 4 * h) * 33 + c] = oaccT[dt][r];
            asm volatile("s_waitcnt lgkmcnt(0)" ::: "memory");
            #pragma unroll
            for (int rr = 0; rr < 16; ++rr) {
                float val = patch[c * 33 + rr * 2 + h];
                oseg[(size_t)(rr * 2 + h) * OUTW + dt * 32 + c] = val;
            }
        }
    }
}

// ---- Kernel C: output_two numerator/denominator (no separate softmax) ------
// grid 256 = b*32 + slice; LDS pre-reduce cuts ws_num atomics 4x.
__global__ __launch_bounds__(256) void o2_kernel(
    const float* __restrict__ input, const float* __restrict__ ws_idot,
    const float* __restrict__ ws_m, float* __restrict__ ws_num,
    float* __restrict__ ws_den)
{
    __shared__ float4 red[256];
    int b = blockIdx.x >> 5, slice = blockIdx.x & 31;
    int t = threadIdx.x;
    int lgrp = t >> 6, d4 = (t & 63) * 4;
    float4 acc = {0.f, 0.f, 0.f, 0.f};
    float esum = 0.f;
    for (int i = 0; i < 16; ++i) {
        int row = b * NL + slice * 64 + lgrp * 16 + i;
        float e = __expf(ws_idot[row] + fmaxf(ws_m[row], ws_m[NB * NL + row]));
        float4 v = *(const float4*)(input + (size_t)row * ND + d4);
        acc.x += e * v.x; acc.y += e * v.y;
        acc.z += e * v.z; acc.w += e * v.w;
        esum += e;
    }
    red[t] = acc;
    __syncthreads();
    if (t < 64) {
        float4 a0 = red[t], a1 = red[t + 64], a2 = red[t + 128], a3 = red[t + 192];
        float* dst = ws_num + b * ND + t * 4;
        atomicAdd(dst + 0, a0.x + a1.x + a2.x + a3.x);
        atomicAdd(dst + 1, a0.y + a1.y + a2.y + a3.y);
        atomicAdd(dst + 2, a0.z + a1.z + a2.z + a3.z);
        atomicAdd(dst + 3, a0.w + a1.w + a2.w + a3.w);
    }
    if ((t & 63) == 0) atomicAdd(ws_den + b, esum);
}

// ---- Kernel D: combine halves + assemble all 4 output segments -------------
__global__ __launch_bounds__(256) void assembly_kernel(
    const float* __restrict__ input, const float* __restrict__ ws_num,
    const float* __restrict__ ws_den, const float* __restrict__ ws_l,
    float* __restrict__ out)
{
    size_t tid = (size_t)blockIdx.x * 256 + threadIdx.x;
    size_t row = tid >> 6;
    int d = (int)(tid & 63) * 4;
    int b = (int)(row >> 11);
    float inv  = 1.0f / (ws_l[row] + ws_l[NB * NL + row]);
    float dinv = 1.0f / ws_den[b];
    float* po = out + row * OUTW;
    float4 in = *(const float4*)(input + row * ND + d);
    float4 pa = *(const float4*)(po + ND + d);
    float4 pb = *(const float4*)(po + 2 * ND + d);
    float4 nu = *(const float4*)(ws_num + b * ND + d);
    float4 o1;
    o1.x = (pa.x + pb.x) * inv; o1.y = (pa.y + pb.y) * inv;
    o1.z = (pa.z + pb.z) * inv; o1.w = (pa.w + pb.w) * inv;
    float4 o2v;
    o2v.x = nu.x * dinv; o2v.y = nu.y * dinv;
    o2v.z = nu.z * dinv; o2v.w = nu.w * dinv;
    *(float4*)(po + d) = in;
    *(float4*)(po + ND + d) = o1;
    float4 q;
    q.x = in.x * o1.x; q.y = in.y * o1.y; q.z = in.z * o1.z; q.w = in.w * o1.w;
    *(float4*)(po + 2 * ND + d) = q;
    float4 r;
    r.x = o2v.x * o1.x; r.y = o2v.y * o1.y; r.z = o2v.z * o1.z; r.w = o2v.w * o1.w;
    *(float4*)(po + 3 * ND + d) = r;
}

// ---- launcher ---------------------------------------------------------------
extern "C" void kernel_launch(void* const* d_in, const int* in_sizes, int n_in,
                              void* d_out, int out_size, void* d_ws, size_t ws_size,
                              hipStream_t stream) {
    const float* input     = (const float*)d_in[0];
    const float* memory    = (const float*)d_in[1];
    const float* mask      = (const float*)d_in[2];
    const float* w_input   = (const float*)d_in[3];
    const float* w_memory  = (const float*)d_in[4];
    const float* dot_scale = (const float*)d_in[5];
    float* out = (float*)d_out;
    char* outc = (char*)d_out;
    float* ws  = (float*)d_ws;

    // ws floats: idot 16K | mbias 16K | l 2x16K | m 2x16K | num 2K | den 8
    float* ws_idot  = ws;
    float* ws_mbias = ws + 16384;
    float* ws_l     = ws + 32768;
    float* ws_m     = ws + 65536;
    float* ws_num   = ws + 98304;
    float* ws_den   = ws + 100352;

    prep_kernel<<<512, 256, 0, stream>>>(memory, mask, w_memory, ws_mbias,
                                         ws_num, outc);
    flash_kernel<<<256, 512, FLASH_LDS, stream>>>(input, dot_scale, w_input,
                                                  ws_mbias, outc, out,
                                                  ws_l, ws_m, ws_idot);
    o2_kernel<<<256, 256, 0, stream>>>(input, ws_idot, ws_m, ws_num, ws_den);
    assembly_kernel<<<4096, 256, 0, stream>>>(input, ws_num, ws_den, ws_l, out);
}